// Round 2
// baseline (12159.526 us; speedup 1.0000x reference)
//
#include <hip/hip_runtime.h>
#include <math.h>

// ---------------------------------------------------------------------------
// RAFT-small forward — round 2: latency-fixed fp32 convs.
// - corr pyramid still never materialized (pool-f2 trick).
// - convs: thread=pixel, 32 out-channels/thread, weights repacked [ci*tap][Co]
//   (wave-uniform -> s_load), branch-free tap fetch, segmented virtual inputs
//   (net | inp | mot | flow-from-coords | r*net), fused epilogues (GRU, +=df).
// ---------------------------------------------------------------------------

static inline int nblk(int n, int b){ return (n + b - 1) / b; }

__global__ void k_ew_tanh(const float* __restrict__ in, float* __restrict__ out, int n){
  int i = blockIdx.x*256 + threadIdx.x;
  if (i < n) out[i] = tanhf(in[i]);
}
__global__ void k_ew_relu(const float* __restrict__ in, float* __restrict__ out, int n){
  int i = blockIdx.x*256 + threadIdx.x;
  if (i < n) out[i] = fmaxf(in[i], 0.0f);
}
__global__ void k_init_coords(float* __restrict__ c, int H, int W){
  int p = blockIdx.x*256 + threadIdx.x;
  int HW = H*W;
  if (p < HW){ c[p] = (float)(p % W); c[HW + p] = (float)(p / W); }
}
__global__ void k_transpose_hwc(const float* __restrict__ in, float* __restrict__ out, int HW){
  int i = blockIdx.x*256 + threadIdx.x;
  if (i < HW*128){ int p = i >> 7, c = i & 127; out[i] = in[c*HW + p]; }
}
__global__ void k_pool_hwc(const float* __restrict__ in, float* __restrict__ out, int H2, int W2){
  int i = blockIdx.x*256 + threadIdx.x;
  int n = H2*W2*128;
  if (i >= n) return;
  int c = i & 127, p = i >> 7;
  int ox = p % W2, oy = p / W2;
  int W = 2*W2;
  const float* b = in + ((size_t)(2*oy)*W + 2*ox)*128 + c;
  out[i] = 0.25f*(b[0] + b[128] + b[(size_t)W*128] + b[(size_t)W*128 + 128]);
}

// weight repack: [Cout][KC] -> [KC][CoutP] (pad channels zeroed)
__global__ void k_repack(const float* __restrict__ w, float* __restrict__ o,
                         int Cout, int CoutP, int KC){
  int idx = blockIdx.x*256 + threadIdx.x;
  if (idx >= KC*CoutP) return;
  int co = idx % CoutP, k = idx / CoutP;
  o[idx] = (co < Cout) ? w[(size_t)co*KC + k] : 0.f;
}
__global__ void k_repack_zr(const float* __restrict__ wz, const float* __restrict__ wr,
                            float* __restrict__ o, int KC){
  int idx = blockIdx.x*256 + threadIdx.x;
  if (idx >= KC*192) return;
  int co = idx % 192, k = idx / 192;
  o[idx] = (co < 96) ? wz[(size_t)co*KC + k] : wr[(size_t)(co-96)*KC + k];
}
__global__ void k_cat2(const float* __restrict__ a, const float* __restrict__ b,
                       float* __restrict__ o, int n){
  int i = blockIdx.x*256 + threadIdx.x;
  if (i < 2*n) o[i] = (i < n) ? a[i] : b[i-n];
}

// corr lookup: one wave per query pixel (validated round 1)
__global__ void k_corr_lookup(const float* __restrict__ f1,
                              const float* __restrict__ l0, const float* __restrict__ l1,
                              const float* __restrict__ l2, const float* __restrict__ l3,
                              const float* __restrict__ coords,
                              float* __restrict__ out, int H, int W)
{
  int q = blockIdx.x;
  int HW = H*W;
  int t = threadIdx.x;
  __shared__ __align__(16) float sf1[128];
  __shared__ float sD[64];
  sf1[t]      = f1[(size_t)t*HW + q];
  sf1[t + 64] = f1[(size_t)(t+64)*HW + q];
  __syncthreads();
  float x = coords[q], y = coords[HW + q];
  const float* const lv[4] = {l0, l1, l2, l3};
  int u = t & 7, v = t >> 3;
  #pragma unroll
  for (int i = 0; i < 4; i++){
    int Wi = W >> i, Hi = H >> i;
    float sc = 1.0f / (float)(1 << i);
    float xs = x*sc, ys = y*sc;
    float fx = floorf(xs), fy = floorf(ys);
    float wx = xs - fx, wy = ys - fy;
    float xf = fx + (float)(u - 3);
    float yf = fy + (float)(v - 3);
    float d = 0.0f;
    if (xf >= 0.0f && xf <= (float)(Wi-1) && yf >= 0.0f && yf <= (float)(Hi-1)){
      const float4* a = (const float4*)sf1;
      const float4* b = (const float4*)(lv[i] + ((size_t)((int)yf)*Wi + (int)xf)*128);
      float acc = 0.0f;
      #pragma unroll
      for (int k = 0; k < 32; k++){
        float4 av = a[k], bv = b[k];
        acc += av.x*bv.x + av.y*bv.y + av.z*bv.z + av.w*bv.w;
      }
      d = acc;
    }
    sD[t] = d;
    __syncthreads();
    if (t < 49){
      int j = t / 7, k = t % 7;
      float val = (1.f-wx)*(1.f-wy)*sD[ k   *8 + j  ]
                +      wx *(1.f-wy)*sD[ k   *8 + j+1]
                + (1.f-wx)*     wy *sD[(k+1)*8 + j  ]
                +      wx *     wy *sD[(k+1)*8 + j+1];
      out[(size_t)(i*49 + t)*HW + q] = val * 0.08838834764831845f;
    }
    __syncthreads();
  }
}

__global__ void k_upflow(const float* __restrict__ cin, float* __restrict__ outp,
                         int Hin, int Win, int Hout, int Wout, float n, int subtract)
{
  int idx = blockIdx.x*256 + threadIdx.x;
  int HWo = Hout*Wout;
  if (idx >= 2*HWo) return;
  int c = idx / HWo;
  int rem = idx - c*HWo;
  int py = rem / Wout, px = rem % Wout;
  float posy = (float)py * (float)(Hin-1) / (float)(Hout-1);
  float posx = (float)px * (float)(Win-1) / (float)(Wout-1);
  int iy = (int)floorf(posy); iy = max(0, min(iy, Hin-2));
  int ix = (int)floorf(posx); ix = max(0, min(ix, Win-2));
  float wy = posy - (float)iy, wx = posx - (float)ix;
  const float* base = cin + (size_t)c*Hin*Win;
  float s00 = 0.f, s10 = 0.f, s01 = 0.f, s11 = 0.f;
  if (subtract){
    if (c == 0){ s00 = (float)ix; s01 = (float)ix; s10 = (float)(ix+1); s11 = (float)(ix+1); }
    else       { s00 = (float)iy; s10 = (float)iy; s01 = (float)(iy+1); s11 = (float)(iy+1); }
  }
  float v00 = base[(size_t)iy*Win + ix]       - s00;
  float v10 = base[(size_t)iy*Win + ix + 1]   - s10;
  float v01 = base[(size_t)(iy+1)*Win + ix]   - s01;
  float v11 = base[(size_t)(iy+1)*Win + ix+1] - s11;
  float val = (1.f-wy)*((1.f-wx)*v00 + wx*v10) + wy*((1.f-wx)*v01 + wx*v11);
  outp[idx] = n * val;
}

// ---------------------------------------------------------------------------
// segmented direct conv
// flag: 0 plain [c0..c1) from a; 1: a=coords, value = coords - grid;
// 2: value = a[cl]*b[cl] (r*net)
// EPI: 0 store; 1 GRU: out = (1-ez)*eold + ez*act(conv); 2: out += conv
// ---------------------------------------------------------------------------
struct Seg { const float* a; const float* b; int c0, c1, flag; };
struct ConvIn { Seg s[4]; };

template<int K, int ACT, int EPI, int CO>
__global__ __launch_bounds__(256, 4)
void k_conv2(ConvIn cin, const float* __restrict__ wre, const float* __restrict__ bias,
             float* __restrict__ out, int Cout, int CoutP, int H, int W,
             const float* __restrict__ ez, const float* __restrict__ eold)
{
  constexpr int P = K/2, KK = K*K;
  const int HW = H*W;
  int pix = blockIdx.x*256 + threadIdx.x;
  if (pix >= HW) return;
  int x = pix % W, y = pix / W;
  int co0 = blockIdx.y * CO;

  float acc[CO];
  #pragma unroll
  for (int u = 0; u < CO; u++) acc[u] = 0.f;

  int po[(K<=3)?KK:1]; float pm[(K<=3)?KK:1], gx[(K<=3)?KK:1], gy[(K<=3)?KK:1];
  if constexpr (K <= 3){
    #pragma unroll
    for (int dy = 0; dy < K; dy++){
      #pragma unroll
      for (int dx = 0; dx < K; dx++){
        int t = dy*K + dx;
        int yy = y + dy - P, xx = x + dx - P;
        bool ok = ((unsigned)yy < (unsigned)H) && ((unsigned)xx < (unsigned)W);
        int yc = min(max(yy, 0), H-1), xc = min(max(xx, 0), W-1);
        po[t] = yc*W + xc;
        pm[t] = ok ? 1.f : 0.f;
        gx[t] = (float)xc; gy[t] = (float)yc;
      }
    }
  }

  #pragma unroll
  for (int s = 0; s < 4; s++){
    int c0 = cin.s[s].c0, c1 = cin.s[s].c1;
    if (c1 <= c0) continue;
    const float* A = cin.s[s].a;
    const float* B = cin.s[s].b;
    int flag = cin.s[s].flag;
    for (int ci = c0; ci < c1; ci++){
      int cl = ci - c0;
      const float* A_ = A + (size_t)cl*HW;
      float v[KK];
      if constexpr (K == 7){
        #pragma unroll
        for (int dy = 0; dy < K; dy++){
          int yy = y + dy - P;
          bool oy = (unsigned)yy < (unsigned)H;
          int yc = min(max(yy, 0), H-1);
          #pragma unroll
          for (int dx = 0; dx < K; dx++){
            int xx = x + dx - P;
            bool ok = oy && ((unsigned)xx < (unsigned)W);
            int xc = min(max(xx, 0), W-1);
            float raw = A_[(size_t)yc*W + xc];
            if (flag == 1) raw -= (cl == 0) ? (float)xc : (float)yc;
            v[dy*K+dx] = ok ? raw : 0.f;
          }
        }
      } else {
        if (flag == 0){
          #pragma unroll
          for (int t = 0; t < KK; t++) v[t] = A_[po[t]] * pm[t];
        } else if (flag == 1){
          bool isx = (cl == 0);
          #pragma unroll
          for (int t = 0; t < KK; t++) v[t] = (A_[po[t]] - (isx ? gx[t] : gy[t])) * pm[t];
        } else {
          const float* B_ = B + (size_t)cl*HW;
          #pragma unroll
          for (int t = 0; t < KK; t++) v[t] = A_[po[t]] * B_[po[t]] * pm[t];
        }
      }
      const float* wp = wre + (size_t)ci*KK*CoutP + co0;
      #pragma unroll
      for (int t = 0; t < KK; t++){
        #pragma unroll
        for (int u = 0; u < CO; u++)
          acc[u] = fmaf(v[t], wp[(size_t)t*CoutP + u], acc[u]);
      }
    }
  }

  #pragma unroll
  for (int u = 0; u < CO; u++){
    int co = co0 + u;
    if (co < Cout){
      float r = acc[u] + bias[co];
      if (ACT == 1) r = fmaxf(r, 0.f);
      if (ACT == 2) r = 1.f/(1.f + expf(-r));
      if (ACT == 3) r = tanhf(r);
      size_t o = (size_t)co*HW + pix;
      if constexpr (EPI == 0) out[o] = r;
      else if constexpr (EPI == 1){ float zz = ez[o]; out[o] = (1.f - zz)*eold[o] + zz*r; }
      else out[o] += r;
    }
  }
}

extern "C" void kernel_launch(void* const* d_in, const int* in_sizes, int n_in,
                              void* d_out, int out_size, void* d_ws, size_t ws_size,
                              hipStream_t stream)
{
  (void)in_sizes; (void)n_in; (void)out_size; (void)ws_size;
  const float* f1s[3]    = {(const float*)d_in[0], (const float*)d_in[2], (const float*)d_in[4]};
  const float* f2s[3]    = {(const float*)d_in[1], (const float*)d_in[3], (const float*)d_in[5]};
  const float* net_in[3] = {(const float*)d_in[6], (const float*)d_in[8], (const float*)d_in[10]};
  const float* inp_in[3] = {(const float*)d_in[7], (const float*)d_in[9], (const float*)d_in[11]};
  const float* Wc1 = (const float*)d_in[12]; const float* bc1 = (const float*)d_in[13];
  const float* Wf1 = (const float*)d_in[14]; const float* bf1 = (const float*)d_in[15];
  const float* Wf2 = (const float*)d_in[16]; const float* bf2 = (const float*)d_in[17];
  const float* Wm  = (const float*)d_in[18]; const float* bm  = (const float*)d_in[19];
  const float* Wz  = (const float*)d_in[20]; const float* bz  = (const float*)d_in[21];
  const float* Wr  = (const float*)d_in[22]; const float* br  = (const float*)d_in[23];
  const float* Wq  = (const float*)d_in[24]; const float* bq  = (const float*)d_in[25];
  const float* Wh1 = (const float*)d_in[26]; const float* bh1 = (const float*)d_in[27];
  const float* Wh2 = (const float*)d_in[28]; const float* bh2 = (const float*)d_in[29];

  const int Hs[3] = {96, 48, 24};

  float* ws = (float*)d_ws;
  size_t off = 0;
  auto alloc = [&](size_t nfl)->float*{
    float* p = ws + off;
    off += (nfl + 3) & ~((size_t)3);
    return p;
  };

  float* f2l[3][4]; float* netP[3][2]; float* inpb[3]; float* coords[3];
  for (int si = 0; si < 3; si++){
    int H = Hs[si], HW = H*H;
    for (int l = 0; l < 4; l++) f2l[si][l] = alloc((size_t)(HW >> (2*l))*128);
    netP[si][0] = alloc((size_t)96*HW);
    netP[si][1] = alloc((size_t)96*HW);
    inpb[si]    = alloc((size_t)64*HW);
    coords[si]  = alloc((size_t)2*HW);
  }
  const int HWm = 96*96;
  float* corrfeat = alloc((size_t)196*HWm);
  float* corb     = alloc((size_t)96*HWm);
  float* flo1     = alloc((size_t)64*HWm);
  float* flo2b    = alloc((size_t)32*HWm);
  float* motb     = alloc((size_t)80*HWm);
  float* zrb      = alloc((size_t)192*HWm);
  float* t128     = alloc((size_t)128*HWm);
  // repacked weights [KC][CoutP]
  float* wc1r = alloc((size_t)196*96);
  float* wf1r = alloc((size_t)2*49*64);
  float* wf2r = alloc((size_t)64*9*32);
  float* wmr  = alloc((size_t)128*9*96);
  float* wzrr = alloc((size_t)242*9*192);
  float* wqr  = alloc((size_t)242*9*96);
  float* wh1r = alloc((size_t)96*9*128);
  float* wh2r = alloc((size_t)128*9*2);
  float* bzr  = alloc(192);

  #define NB(n) dim3((unsigned)nblk((n), 256))

  // weight repacks
  k_repack<<<NB(196*96), 256, 0, stream>>>(Wc1, wc1r, 96, 96, 196);
  k_repack<<<NB(2*49*64), 256, 0, stream>>>(Wf1, wf1r, 64, 64, 2*49);
  k_repack<<<NB(64*9*32), 256, 0, stream>>>(Wf2, wf2r, 32, 32, 64*9);
  k_repack<<<NB(128*9*96), 256, 0, stream>>>(Wm, wmr, 80, 96, 128*9);
  k_repack_zr<<<NB(242*9*192), 256, 0, stream>>>(Wz, Wr, wzrr, 242*9);
  k_repack<<<NB(242*9*96), 256, 0, stream>>>(Wq, wqr, 96, 96, 242*9);
  k_repack<<<NB(96*9*128), 256, 0, stream>>>(Wh1, wh1r, 128, 128, 96*9);
  k_repack<<<NB(128*9*2), 256, 0, stream>>>(Wh2, wh2r, 2, 2, 128*9);
  k_cat2<<<dim3(1), 256, 0, stream>>>(bz, br, bzr, 96);

  // per-scale init
  for (int si = 0; si < 3; si++){
    int H = Hs[si], HW = H*H;
    k_ew_tanh<<<NB(96*HW), 256, 0, stream>>>(net_in[si], netP[si][0], 96*HW);
    k_ew_relu<<<NB(64*HW), 256, 0, stream>>>(inp_in[si], inpb[si], 64*HW);
    k_init_coords<<<NB(HW), 256, 0, stream>>>(coords[si], H, H);
    k_transpose_hwc<<<NB(HW*128), 256, 0, stream>>>(f2s[si], f2l[si][0], HW);
    for (int l = 1; l < 4; l++){
      int Hl = H >> l;
      k_pool_hwc<<<NB(Hl*Hl*128), 256, 0, stream>>>(f2l[si][l-1], f2l[si][l], Hl, Hl);
    }
  }

  int cur[3] = {0, 0, 0};
  const int seq[6] = {2, 2, 1, 1, 0, 0};
  for (int it = 0; it < 6; it++){
    int si = seq[it];
    int H = Hs[si], W = H, HW = H*W;
    float s = (si == 0) ? 2.0f : ((si == 1) ? 4.0f : 8.0f);
    float* netc = netP[si][cur[si]];
    float* netn = netP[si][cur[si]^1];
    float* co   = coords[si];
    unsigned gx = (unsigned)nblk(HW, 256);

    k_corr_lookup<<<dim3((unsigned)HW), 64, 0, stream>>>(
        f1s[si], f2l[si][0], f2l[si][1], f2l[si][2], f2l[si][3], co, corrfeat, H, W);

    ConvIn I;
    // convc1 (1x1, 196->96, relu)
    I = ConvIn{{ {corrfeat,nullptr,0,196,0},{nullptr,nullptr,0,0,0},{nullptr,nullptr,0,0,0},{nullptr,nullptr,0,0,0} }};
    k_conv2<1,1,0,32><<<dim3(gx,3), 256, 0, stream>>>(I, wc1r, bc1, corb, 96, 96, H, W, nullptr, nullptr);
    // convf1 (7x7, flow(2)->64, relu); flow from coords
    I = ConvIn{{ {co,nullptr,0,2,1},{nullptr,nullptr,0,0,0},{nullptr,nullptr,0,0,0},{nullptr,nullptr,0,0,0} }};
    k_conv2<7,1,0,16><<<dim3(gx,4), 256, 0, stream>>>(I, wf1r, bf1, flo1, 64, 64, H, W, nullptr, nullptr);
    // convf2 (3x3, 64->32, relu)
    I = ConvIn{{ {flo1,nullptr,0,64,0},{nullptr,nullptr,0,0,0},{nullptr,nullptr,0,0,0},{nullptr,nullptr,0,0,0} }};
    k_conv2<3,1,0,16><<<dim3(gx,2), 256, 0, stream>>>(I, wf2r, bf2, flo2b, 32, 32, H, W, nullptr, nullptr);
    // convm (3x3, [cor96|flo32]->80, relu)
    I = ConvIn{{ {corb,nullptr,0,96,0},{flo2b,nullptr,96,128,0},{nullptr,nullptr,0,0,0},{nullptr,nullptr,0,0,0} }};
    k_conv2<3,1,0,32><<<dim3(gx,3), 256, 0, stream>>>(I, wmr, bm, motb, 80, 96, H, W, nullptr, nullptr);
    // z+r fused (3x3, [net|inp|mot|flow]->192, sigmoid)
    I = ConvIn{{ {netc,nullptr,0,96,0},{inpb[si],nullptr,96,160,0},{motb,nullptr,160,240,0},{co,nullptr,240,242,1} }};
    k_conv2<3,2,0,32><<<dim3(gx,6), 256, 0, stream>>>(I, wzrr, bzr, zrb, 192, 192, H, W, nullptr, nullptr);
    // q (3x3, [r*net|inp|mot|flow]->96, tanh) + GRU epilogue -> netn
    I = ConvIn{{ {zrb + (size_t)96*HW, netc, 0,96,2},{inpb[si],nullptr,96,160,0},{motb,nullptr,160,240,0},{co,nullptr,240,242,1} }};
    k_conv2<3,3,1,32><<<dim3(gx,3), 256, 0, stream>>>(I, wqr, bq, netn, 96, 96, H, W, zrb, netc);
    // fh1 (3x3, 96->128, relu)
    I = ConvIn{{ {netn,nullptr,0,96,0},{nullptr,nullptr,0,0,0},{nullptr,nullptr,0,0,0},{nullptr,nullptr,0,0,0} }};
    k_conv2<3,1,0,32><<<dim3(gx,4), 256, 0, stream>>>(I, wh1r, bh1, t128, 128, 128, H, W, nullptr, nullptr);
    // fh2 (3x3, 128->2) += into coords
    I = ConvIn{{ {t128,nullptr,0,128,0},{nullptr,nullptr,0,0,0},{nullptr,nullptr,0,0,0},{nullptr,nullptr,0,0,0} }};
    k_conv2<3,0,2,2><<<dim3(gx,1), 256, 0, stream>>>(I, wh2r, bh2, co, 2, 2, H, W, nullptr, nullptr);

    // prediction
    k_upflow<<<NB(2*192*192), 256, 0, stream>>>(co, (float*)d_out + (size_t)it*2*192*192,
                                                H, W, 192, 192, s, 1);
    if (si > 0){
      int Hf = Hs[si-1];
      k_upflow<<<NB(2*Hf*Hf), 256, 0, stream>>>(co, coords[si-1], H, W, Hf, Hf, 2.0f, 0);
    }
    cur[si] ^= 1;
  }
  #undef NB
}

// Round 3
// 10255.757 us; speedup vs baseline: 1.1856x; 1.1856x over previous
//
#include <hip/hip_runtime.h>
#include <math.h>

// ---------------------------------------------------------------------------
// RAFT-small forward — round 3: fp32 convs, spill-fixed + pipelined.
// r2 failure: __launch_bounds__(256,4) + 32 acc => VGPR cap 64 => scratch
// spill (VALUBusy 1%). Now: 2px x 8co = 16 acc, bounds (256,2), explicit
// bufA/bufB double-buffer over ci, split-K for fh2, f1 in HWC for corr.
// ---------------------------------------------------------------------------

static inline int nblk(int n, int b){ return (n + b - 1) / b; }

__global__ void k_ew_tanh(const float* __restrict__ in, float* __restrict__ out, int n){
  int i = blockIdx.x*256 + threadIdx.x;
  if (i < n) out[i] = tanhf(in[i]);
}
__global__ void k_ew_relu(const float* __restrict__ in, float* __restrict__ out, int n){
  int i = blockIdx.x*256 + threadIdx.x;
  if (i < n) out[i] = fmaxf(in[i], 0.0f);
}
__global__ void k_init_coords(float* __restrict__ c, int H, int W){
  int p = blockIdx.x*256 + threadIdx.x;
  int HW = H*W;
  if (p < HW){ c[p] = (float)(p % W); c[HW + p] = (float)(p / W); }
}
__global__ void k_transpose_hwc(const float* __restrict__ in, float* __restrict__ out, int HW){
  int i = blockIdx.x*256 + threadIdx.x;
  if (i < HW*128){ int p = i >> 7, c = i & 127; out[i] = in[c*HW + p]; }
}
__global__ void k_pool_hwc(const float* __restrict__ in, float* __restrict__ out, int H2, int W2){
  int i = blockIdx.x*256 + threadIdx.x;
  int n = H2*W2*128;
  if (i >= n) return;
  int c = i & 127, p = i >> 7;
  int ox = p % W2, oy = p / W2;
  int W = 2*W2;
  const float* b = in + ((size_t)(2*oy)*W + 2*ox)*128 + c;
  out[i] = 0.25f*(b[0] + b[128] + b[(size_t)W*128] + b[(size_t)W*128 + 128]);
}
// [Cout][KC] -> [KC][CoutP]
__global__ void k_repack(const float* __restrict__ w, float* __restrict__ o,
                         int Cout, int CoutP, int KC){
  int idx = blockIdx.x*256 + threadIdx.x;
  if (idx >= KC*CoutP) return;
  int co = idx % CoutP, k = idx / CoutP;
  o[idx] = (co < Cout) ? w[(size_t)co*KC + k] : 0.f;
}
__global__ void k_repack_zr(const float* __restrict__ wz, const float* __restrict__ wr,
                            float* __restrict__ o, int KC){
  int idx = blockIdx.x*256 + threadIdx.x;
  if (idx >= KC*192) return;
  int co = idx % 192, k = idx / 192;
  o[idx] = (co < 96) ? wz[(size_t)co*KC + k] : wr[(size_t)(co-96)*KC + k];
}
__global__ void k_cat2(const float* __restrict__ a, const float* __restrict__ b,
                       float* __restrict__ o, int n){
  int i = blockIdx.x*256 + threadIdx.x;
  if (i < 2*n) o[i] = (i < n) ? a[i] : b[i-n];
}

// corr lookup: one wave per query pixel; f1 in HWC (coalesced block load)
__global__ void k_corr_lookup(const float* __restrict__ f1h,    // [HW][128]
                              const float* __restrict__ l0, const float* __restrict__ l1,
                              const float* __restrict__ l2, const float* __restrict__ l3,
                              const float* __restrict__ coords,
                              float* __restrict__ out, int H, int W)
{
  int q = blockIdx.x;
  int HW = H*W;
  int t = threadIdx.x;
  __shared__ __align__(16) float sf1[128];
  __shared__ float sD[64];
  sf1[t]      = f1h[(size_t)q*128 + t];
  sf1[t + 64] = f1h[(size_t)q*128 + 64 + t];
  __syncthreads();
  float x = coords[q], y = coords[HW + q];
  const float* const lv[4] = {l0, l1, l2, l3};
  int u = t & 7, v = t >> 3;
  #pragma unroll
  for (int i = 0; i < 4; i++){
    int Wi = W >> i, Hi = H >> i;
    float sc = 1.0f / (float)(1 << i);
    float xs = x*sc, ys = y*sc;
    float fx = floorf(xs), fy = floorf(ys);
    float wx = xs - fx, wy = ys - fy;
    float xf = fx + (float)(u - 3);
    float yf = fy + (float)(v - 3);
    float d = 0.0f;
    if (xf >= 0.0f && xf <= (float)(Wi-1) && yf >= 0.0f && yf <= (float)(Hi-1)){
      const float4* a = (const float4*)sf1;
      const float4* b = (const float4*)(lv[i] + ((size_t)((int)yf)*Wi + (int)xf)*128);
      float acc = 0.0f;
      #pragma unroll
      for (int k = 0; k < 32; k++){
        float4 av = a[k], bv = b[k];
        acc += av.x*bv.x + av.y*bv.y + av.z*bv.z + av.w*bv.w;
      }
      d = acc;
    }
    sD[t] = d;
    __syncthreads();
    if (t < 49){
      int j = t / 7, k = t % 7;
      float val = (1.f-wx)*(1.f-wy)*sD[ k   *8 + j  ]
                +      wx *(1.f-wy)*sD[ k   *8 + j+1]
                + (1.f-wx)*     wy *sD[(k+1)*8 + j  ]
                +      wx *     wy *sD[(k+1)*8 + j+1];
      out[(size_t)(i*49 + t)*HW + q] = val * 0.08838834764831845f;
    }
    __syncthreads();
  }
}

__global__ void k_upflow(const float* __restrict__ cin, float* __restrict__ outp,
                         int Hin, int Win, int Hout, int Wout, float n, int subtract)
{
  int idx = blockIdx.x*256 + threadIdx.x;
  int HWo = Hout*Wout;
  if (idx >= 2*HWo) return;
  int c = idx / HWo;
  int rem = idx - c*HWo;
  int py = rem / Wout, px = rem % Wout;
  float posy = (float)py * (float)(Hin-1) / (float)(Hout-1);
  float posx = (float)px * (float)(Win-1) / (float)(Wout-1);
  int iy = (int)floorf(posy); iy = max(0, min(iy, Hin-2));
  int ix = (int)floorf(posx); ix = max(0, min(ix, Win-2));
  float wy = posy - (float)iy, wx = posx - (float)ix;
  const float* base = cin + (size_t)c*Hin*Win;
  float s00 = 0.f, s10 = 0.f, s01 = 0.f, s11 = 0.f;
  if (subtract){
    if (c == 0){ s00 = (float)ix; s01 = (float)ix; s10 = (float)(ix+1); s11 = (float)(ix+1); }
    else       { s00 = (float)iy; s10 = (float)iy; s01 = (float)(iy+1); s11 = (float)(iy+1); }
  }
  float v00 = base[(size_t)iy*Win + ix]       - s00;
  float v10 = base[(size_t)iy*Win + ix + 1]   - s10;
  float v01 = base[(size_t)(iy+1)*Win + ix]   - s01;
  float v11 = base[(size_t)(iy+1)*Win + ix+1] - s11;
  float val = (1.f-wy)*((1.f-wx)*v00 + wx*v10) + wy*((1.f-wx)*v01 + wx*v11);
  outp[idx] = n * val;
}

// ---------------------------------------------------------------------------
// conv helpers: load K x (K+1) tap window for 2 consecutive pixels, masked.
// flag 0: plain; 1: coords - grid; 2: a*b (r*net)
// ---------------------------------------------------------------------------
template<int K>
__device__ __forceinline__ void conv_loadv(const float* __restrict__ A_,
                                           const float* __restrict__ B_,
                                           int flag, int x0, int y, int H, int W, int cl,
                                           float (&buf)[K][K+1])
{
  const int P = K/2;
  #pragma unroll
  for (int dy = 0; dy < K; dy++){
    int yy = y + dy - P;
    float rm = ((unsigned)yy < (unsigned)H) ? 1.f : 0.f;
    int yc = min(max(yy, 0), H-1);
    const float* rp = A_ + (size_t)yc*W;
    const float* rq = B_ + (size_t)yc*W;
    #pragma unroll
    for (int c = 0; c < K+1; c++){
      int xx = x0 + c - P;
      float m = rm * (((unsigned)xx < (unsigned)W) ? 1.f : 0.f);
      int xc = min(max(xx, 0), W-1);
      float v = rp[xc];
      if (flag == 1) v -= (cl == 0) ? (float)xx : (float)yy;
      if (flag == 2) v *= rq[xc];
      buf[dy][c] = v * m;
    }
  }
}

template<int K, int CO>
__device__ __forceinline__ void conv_fma(const float* __restrict__ wre, int ci, int CoutP,
                                         int co0, const float (&buf)[K][K+1],
                                         float (&acc)[2][CO])
{
  #pragma unroll
  for (int t = 0; t < K*K; t++){
    const float* wp = wre + ((size_t)ci*K*K + (size_t)t)*CoutP + co0;
    float wv[CO];
    #pragma unroll
    for (int u = 0; u < CO; u++) wv[u] = wp[u];
    const int dy = t / K, dx = t % K;
    #pragma unroll
    for (int u = 0; u < CO; u++){
      acc[0][u] = fmaf(buf[dy][dx],     wv[u], acc[0][u]);
      acc[1][u] = fmaf(buf[dy][dx + 1], wv[u], acc[1][u]);
    }
  }
}

struct Seg { const float* a; const float* b; int c0, c1, flag; };
struct ConvIn { Seg s[4]; };

// ACT: 0 none, 1 relu, 2 sigmoid, 3 tanh. EPI: 0 store; 1 GRU.
template<int K, int ACT, int EPI, int CO>
__global__ __launch_bounds__(256, 2)
void k_conv3(ConvIn cin, const float* __restrict__ wre, const float* __restrict__ bias,
             float* __restrict__ out, int CoutP, int H, int W,
             const float* __restrict__ ez, const float* __restrict__ eold)
{
  const int HW = H*W;
  int pix0 = (blockIdx.x*256 + threadIdx.x)*2;
  if (pix0 >= HW) return;
  int x0 = pix0 % W, y = pix0 / W;
  int co0 = blockIdx.y*CO;

  float acc[2][CO];
  #pragma unroll
  for (int j = 0; j < 2; j++)
    #pragma unroll
    for (int u = 0; u < CO; u++) acc[j][u] = 0.f;

  float bufA[K][K+1], bufB[K][K+1];

  #pragma unroll
  for (int s = 0; s < 4; s++){
    int c0 = cin.s[s].c0, c1 = cin.s[s].c1;
    if (c1 <= c0) continue;
    const float* A = cin.s[s].a;
    const float* B = cin.s[s].b ? cin.s[s].b : cin.s[s].a;
    int flag = cin.s[s].flag;
    conv_loadv<K>(A, B, flag, x0, y, H, W, 0, bufA);
    for (int ci = c0; ci < c1; ci += 2){
      int cl = ci - c0;
      if (ci + 1 < c1)
        conv_loadv<K>(A + (size_t)(cl+1)*HW, B + (size_t)(cl+1)*HW, flag, x0, y, H, W, cl+1, bufB);
      conv_fma<K, CO>(wre, ci, CoutP, co0, bufA, acc);
      if (ci + 2 < c1)
        conv_loadv<K>(A + (size_t)(cl+2)*HW, B + (size_t)(cl+2)*HW, flag, x0, y, H, W, cl+2, bufA);
      if (ci + 1 < c1)
        conv_fma<K, CO>(wre, ci+1, CoutP, co0, bufB, acc);
    }
  }

  #pragma unroll
  for (int u = 0; u < CO; u++){
    float bb = bias[co0 + u];
    #pragma unroll
    for (int j = 0; j < 2; j++){
      float r = acc[j][u] + bb;
      if (ACT == 1) r = fmaxf(r, 0.f);
      if (ACT == 2) r = 1.f/(1.f + expf(-r));
      if (ACT == 3) r = tanhf(r);
      size_t o = (size_t)(co0 + u)*HW + pix0 + j;
      if constexpr (EPI == 1){ float zz = ez[o]; out[o] = (1.f - zz)*eold[o] + zz*r; }
      else out[o] = r;
    }
  }
}

// fh2 split-K: Cin=128 in 8 chunks of 16 (blockIdx.y), Cout=2, partials out.
__global__ __launch_bounds__(256, 2)
void k_fh2_part(const float* __restrict__ in, const float* __restrict__ wre,
                float* __restrict__ part, int H, int W)
{
  const int HW = H*W;
  int pix0 = (blockIdx.x*256 + threadIdx.x)*2;
  if (pix0 >= HW) return;
  int x0 = pix0 % W, y = pix0 / W;
  int ck = blockIdx.y, c0 = ck*16;
  float acc[2][2] = {{0.f,0.f},{0.f,0.f}};
  float bufA[3][4], bufB[3][4];
  conv_loadv<3>(in + (size_t)c0*HW, in, 0, x0, y, H, W, 0, bufA);
  for (int ci = c0; ci < c0 + 16; ci += 2){
    conv_loadv<3>(in + (size_t)(ci+1)*HW, in, 0, x0, y, H, W, 0, bufB);
    conv_fma<3,2>(wre, ci, 2, 0, bufA, acc);
    if (ci + 2 < c0 + 16)
      conv_loadv<3>(in + (size_t)(ci+2)*HW, in, 0, x0, y, H, W, 0, bufA);
    conv_fma<3,2>(wre, ci+1, 2, 0, bufB, acc);
  }
  #pragma unroll
  for (int u = 0; u < 2; u++)
    #pragma unroll
    for (int j = 0; j < 2; j++)
      part[((size_t)ck*2 + u)*HW + pix0 + j] = acc[j][u];
}
__global__ void k_fh2_red(const float* __restrict__ part, const float* __restrict__ bias,
                          float* __restrict__ coords, int HW)
{
  int i = blockIdx.x*256 + threadIdx.x;
  if (i >= 2*HW) return;
  int co = i / HW, p = i - co*HW;
  float s = bias[co];
  #pragma unroll
  for (int ck = 0; ck < 8; ck++) s += part[((size_t)ck*2 + co)*HW + p];
  coords[i] += s;
}

extern "C" void kernel_launch(void* const* d_in, const int* in_sizes, int n_in,
                              void* d_out, int out_size, void* d_ws, size_t ws_size,
                              hipStream_t stream)
{
  (void)in_sizes; (void)n_in; (void)out_size; (void)ws_size;
  const float* f1s[3]    = {(const float*)d_in[0], (const float*)d_in[2], (const float*)d_in[4]};
  const float* f2s[3]    = {(const float*)d_in[1], (const float*)d_in[3], (const float*)d_in[5]};
  const float* net_in[3] = {(const float*)d_in[6], (const float*)d_in[8], (const float*)d_in[10]};
  const float* inp_in[3] = {(const float*)d_in[7], (const float*)d_in[9], (const float*)d_in[11]};
  const float* Wc1 = (const float*)d_in[12]; const float* bc1 = (const float*)d_in[13];
  const float* Wf1 = (const float*)d_in[14]; const float* bf1 = (const float*)d_in[15];
  const float* Wf2 = (const float*)d_in[16]; const float* bf2 = (const float*)d_in[17];
  const float* Wm  = (const float*)d_in[18]; const float* bm  = (const float*)d_in[19];
  const float* Wz  = (const float*)d_in[20]; const float* bz  = (const float*)d_in[21];
  const float* Wr  = (const float*)d_in[22]; const float* br  = (const float*)d_in[23];
  const float* Wq  = (const float*)d_in[24]; const float* bq  = (const float*)d_in[25];
  const float* Wh1 = (const float*)d_in[26]; const float* bh1 = (const float*)d_in[27];
  const float* Wh2 = (const float*)d_in[28]; const float* bh2 = (const float*)d_in[29];

  const int Hs[3] = {96, 48, 24};

  float* ws = (float*)d_ws;
  size_t off = 0;
  auto alloc = [&](size_t nfl)->float*{
    float* p = ws + off;
    off += (nfl + 3) & ~((size_t)3);
    return p;
  };

  float* f2l[3][4]; float* f1h[3]; float* netP[3][2]; float* inpb[3]; float* coords[3];
  for (int si = 0; si < 3; si++){
    int H = Hs[si], HW = H*H;
    for (int l = 0; l < 4; l++) f2l[si][l] = alloc((size_t)(HW >> (2*l))*128);
    f1h[si]     = alloc((size_t)HW*128);
    netP[si][0] = alloc((size_t)96*HW);
    netP[si][1] = alloc((size_t)96*HW);
    inpb[si]    = alloc((size_t)64*HW);
    coords[si]  = alloc((size_t)2*HW);
  }
  const int HWm = 96*96;
  float* corrfeat = alloc((size_t)196*HWm);
  float* corb     = alloc((size_t)96*HWm);
  float* flo1     = alloc((size_t)64*HWm);
  float* flo2b    = alloc((size_t)32*HWm);
  float* motb     = alloc((size_t)80*HWm);
  float* zrb      = alloc((size_t)192*HWm);
  float* t128     = alloc((size_t)128*HWm);
  float* part     = alloc((size_t)16*HWm);
  float* wc1r = alloc((size_t)196*96);
  float* wf1r = alloc((size_t)2*49*64);
  float* wf2r = alloc((size_t)64*9*32);
  float* wmr  = alloc((size_t)128*9*80);
  float* wzrr = alloc((size_t)242*9*192);
  float* wqr  = alloc((size_t)242*9*96);
  float* wh1r = alloc((size_t)96*9*128);
  float* wh2r = alloc((size_t)128*9*2);
  float* bzr  = alloc(192);

  #define NB(n) dim3((unsigned)nblk((n), 256))

  k_repack<<<NB(196*96), 256, 0, stream>>>(Wc1, wc1r, 96, 96, 196);
  k_repack<<<NB(2*49*64), 256, 0, stream>>>(Wf1, wf1r, 64, 64, 2*49);
  k_repack<<<NB(64*9*32), 256, 0, stream>>>(Wf2, wf2r, 32, 32, 64*9);
  k_repack<<<NB(128*9*80), 256, 0, stream>>>(Wm, wmr, 80, 80, 128*9);
  k_repack_zr<<<NB(242*9*192), 256, 0, stream>>>(Wz, Wr, wzrr, 242*9);
  k_repack<<<NB(242*9*96), 256, 0, stream>>>(Wq, wqr, 96, 96, 242*9);
  k_repack<<<NB(96*9*128), 256, 0, stream>>>(Wh1, wh1r, 128, 128, 96*9);
  k_repack<<<NB(128*9*2), 256, 0, stream>>>(Wh2, wh2r, 2, 2, 128*9);
  k_cat2<<<dim3(1), 256, 0, stream>>>(bz, br, bzr, 96);

  for (int si = 0; si < 3; si++){
    int H = Hs[si], HW = H*H;
    k_ew_tanh<<<NB(96*HW), 256, 0, stream>>>(net_in[si], netP[si][0], 96*HW);
    k_ew_relu<<<NB(64*HW), 256, 0, stream>>>(inp_in[si], inpb[si], 64*HW);
    k_init_coords<<<NB(HW), 256, 0, stream>>>(coords[si], H, H);
    k_transpose_hwc<<<NB(HW*128), 256, 0, stream>>>(f2s[si], f2l[si][0], HW);
    k_transpose_hwc<<<NB(HW*128), 256, 0, stream>>>(f1s[si], f1h[si], HW);
    for (int l = 1; l < 4; l++){
      int Hl = H >> l;
      k_pool_hwc<<<NB(Hl*Hl*128), 256, 0, stream>>>(f2l[si][l-1], f2l[si][l], Hl, Hl);
    }
  }

  int cur[3] = {0, 0, 0};
  const int seq[6] = {2, 2, 1, 1, 0, 0};
  for (int it = 0; it < 6; it++){
    int si = seq[it];
    int H = Hs[si], W = H, HW = H*W;
    float s = (si == 0) ? 2.0f : ((si == 1) ? 4.0f : 8.0f);
    float* netc = netP[si][cur[si]];
    float* netn = netP[si][cur[si]^1];
    float* co   = coords[si];
    unsigned gx = (unsigned)nblk(HW/2, 256);

    k_corr_lookup<<<dim3((unsigned)HW), 64, 0, stream>>>(
        f1h[si], f2l[si][0], f2l[si][1], f2l[si][2], f2l[si][3], co, corrfeat, H, W);

    ConvIn I;
    Seg z0 = {nullptr, nullptr, 0, 0, 0};
    // convc1 (1x1, 196->96, relu)
    I = ConvIn{{ {corrfeat,nullptr,0,196,0}, z0, z0, z0 }};
    k_conv3<1,1,0,8><<<dim3(gx,12), 256, 0, stream>>>(I, wc1r, bc1, corb, 96, H, W, nullptr, nullptr);
    // convf1 (7x7, flow(2)->64, relu); flow from coords
    I = ConvIn{{ {co,nullptr,0,2,1}, z0, z0, z0 }};
    k_conv3<7,1,0,8><<<dim3(gx,8), 256, 0, stream>>>(I, wf1r, bf1, flo1, 64, H, W, nullptr, nullptr);
    // convf2 (3x3, 64->32, relu)
    I = ConvIn{{ {flo1,nullptr,0,64,0}, z0, z0, z0 }};
    k_conv3<3,1,0,8><<<dim3(gx,4), 256, 0, stream>>>(I, wf2r, bf2, flo2b, 32, H, W, nullptr, nullptr);
    // convm (3x3, [cor96|flo32]->80, relu)
    I = ConvIn{{ {corb,nullptr,0,96,0},{flo2b,nullptr,96,128,0}, z0, z0 }};
    k_conv3<3,1,0,8><<<dim3(gx,10), 256, 0, stream>>>(I, wmr, bm, motb, 80, H, W, nullptr, nullptr);
    // z+r fused (3x3, [net|inp|mot|flow]->192, sigmoid)
    I = ConvIn{{ {netc,nullptr,0,96,0},{inpb[si],nullptr,96,160,0},{motb,nullptr,160,240,0},{co,nullptr,240,242,1} }};
    k_conv3<3,2,0,8><<<dim3(gx,24), 256, 0, stream>>>(I, wzrr, bzr, zrb, 192, H, W, nullptr, nullptr);
    // q (3x3, [r*net|inp|mot|flow]->96, tanh) + GRU epilogue -> netn
    I = ConvIn{{ {zrb + (size_t)96*HW, netc, 0,96,2},{inpb[si],nullptr,96,160,0},{motb,nullptr,160,240,0},{co,nullptr,240,242,1} }};
    k_conv3<3,3,1,8><<<dim3(gx,12), 256, 0, stream>>>(I, wqr, bq, netn, 96, H, W, zrb, netc);
    // fh1 (3x3, 96->128, relu)
    I = ConvIn{{ {netn,nullptr,0,96,0}, z0, z0, z0 }};
    k_conv3<3,1,0,8><<<dim3(gx,16), 256, 0, stream>>>(I, wh1r, bh1, t128, 128, H, W, nullptr, nullptr);
    // fh2 (3x3, 128->2) split-K + reduce into coords
    k_fh2_part<<<dim3(gx,8), 256, 0, stream>>>(t128, wh2r, part, H, W);
    k_fh2_red<<<NB(2*HW), 256, 0, stream>>>(part, bh2, co, HW);

    k_upflow<<<NB(2*192*192), 256, 0, stream>>>(co, (float*)d_out + (size_t)it*2*192*192,
                                                H, W, 192, 192, s, 1);
    if (si > 0){
      int Hf = Hs[si-1];
      k_upflow<<<NB(2*Hf*Hf), 256, 0, stream>>>(co, coords[si-1], H, W, Hf, Hf, 2.0f, 0);
    }
    cur[si] ^= 1;
  }
  #undef NB
}

// Round 5
// 1761.388 us; speedup vs baseline: 6.9034x; 5.8225x over previous
//
#include <hip/hip_runtime.h>
#include <hip/hip_bf16.h>
#include <math.h>

// ---------------------------------------------------------------------------
// RAFT-small forward — round 5: split-bf16 MFMA implicit GEMM (3-term).
// r4 failed absmax 19 (bf16 input quantization 0.39% amplified ~5000x by the
// 6-iter GRU recurrence; layouts verified correct). Now every value is split
// x = hi + lo (both bf16) and D = Ah*Bh + Al*Bh + Ah*Bl, fp32 accum
// => per-product rel err ~2^-16, predicted absmax ~1.
// Fragment blocks: 128 short8 per (mt,kt): hi at [lane], lo at [lane+64].
// ---------------------------------------------------------------------------

typedef __attribute__((ext_vector_type(8))) short short8;
typedef __attribute__((ext_vector_type(4))) float f32x4;

static inline int nblk(int n, int b){ return (n + b - 1) / b; }

__device__ __forceinline__ short bf16bits(float v){
  __hip_bfloat16 h = __float2bfloat16(v);
  return *reinterpret_cast<short*>(&h);
}
__device__ __forceinline__ float bf2f(short s){
  unsigned u = ((unsigned)(unsigned short)s) << 16;
  return *reinterpret_cast<float*>(&u);
}

__global__ void k_ew_tanh(const float* __restrict__ in, float* __restrict__ out, int n){
  int i = blockIdx.x*256 + threadIdx.x;
  if (i < n) out[i] = tanhf(in[i]);
}
__global__ void k_ew_relu(const float* __restrict__ in, float* __restrict__ out, int n){
  int i = blockIdx.x*256 + threadIdx.x;
  if (i < n) out[i] = fmaxf(in[i], 0.0f);
}
__global__ void k_init_coords(float* __restrict__ c, int H, int W){
  int p = blockIdx.x*256 + threadIdx.x;
  int HW = H*W;
  if (p < HW){ c[p] = (float)(p % W); c[HW + p] = (float)(p / W); }
}
__global__ void k_transpose_hwc(const float* __restrict__ in, float* __restrict__ out, int HW){
  int i = blockIdx.x*256 + threadIdx.x;
  if (i < HW*128){ int p = i >> 7, c = i & 127; out[i] = in[c*HW + p]; }
}
__global__ void k_pool_hwc(const float* __restrict__ in, float* __restrict__ out, int H2, int W2){
  int i = blockIdx.x*256 + threadIdx.x;
  int n = H2*W2*128;
  if (i >= n) return;
  int c = i & 127, p = i >> 7;
  int ox = p % W2, oy = p / W2;
  int W = 2*W2;
  const float* b = in + ((size_t)(2*oy)*W + 2*ox)*128 + c;
  out[i] = 0.25f*(b[0] + b[128] + b[(size_t)W*128] + b[(size_t)W*128 + 128]);
}
__global__ void k_cat2(const float* __restrict__ a, const float* __restrict__ b,
                       float* __restrict__ o, int n){
  int i = blockIdx.x*256 + threadIdx.x;
  if (i < 2*n) o[i] = (i < n) ? a[i] : b[i-n];
}

// corr lookup: one wave per query pixel (validated r1/r3)
__global__ void k_corr_lookup(const float* __restrict__ f1h,
                              const float* __restrict__ l0, const float* __restrict__ l1,
                              const float* __restrict__ l2, const float* __restrict__ l3,
                              const float* __restrict__ coords,
                              float* __restrict__ out, int H, int W)
{
  int q = blockIdx.x;
  int HW = H*W;
  int t = threadIdx.x;
  __shared__ __align__(16) float sf1[128];
  __shared__ float sD[64];
  sf1[t]      = f1h[(size_t)q*128 + t];
  sf1[t + 64] = f1h[(size_t)q*128 + 64 + t];
  __syncthreads();
  float x = coords[q], y = coords[HW + q];
  const float* const lv[4] = {l0, l1, l2, l3};
  int u = t & 7, v = t >> 3;
  #pragma unroll
  for (int i = 0; i < 4; i++){
    int Wi = W >> i, Hi = H >> i;
    float sc = 1.0f / (float)(1 << i);
    float xs = x*sc, ys = y*sc;
    float fx = floorf(xs), fy = floorf(ys);
    float wx = xs - fx, wy = ys - fy;
    float xf = fx + (float)(u - 3);
    float yf = fy + (float)(v - 3);
    float d = 0.0f;
    if (xf >= 0.0f && xf <= (float)(Wi-1) && yf >= 0.0f && yf <= (float)(Hi-1)){
      const float4* a = (const float4*)sf1;
      const float4* b = (const float4*)(lv[i] + ((size_t)((int)yf)*Wi + (int)xf)*128);
      float acc = 0.0f;
      #pragma unroll
      for (int k = 0; k < 32; k++){
        float4 av = a[k], bv = b[k];
        acc += av.x*bv.x + av.y*bv.y + av.z*bv.z + av.w*bv.w;
      }
      d = acc;
    }
    sD[t] = d;
    __syncthreads();
    if (t < 49){
      int j = t / 7, k = t % 7;
      float val = (1.f-wx)*(1.f-wy)*sD[ k   *8 + j  ]
                +      wx *(1.f-wy)*sD[ k   *8 + j+1]
                + (1.f-wx)*     wy *sD[(k+1)*8 + j  ]
                +      wx *     wy *sD[(k+1)*8 + j+1];
      out[(size_t)(i*49 + t)*HW + q] = val * 0.08838834764831845f;
    }
    __syncthreads();
  }
}

__global__ void k_upflow(const float* __restrict__ cin, float* __restrict__ outp,
                         int Hin, int Win, int Hout, int Wout, float n, int subtract)
{
  int idx = blockIdx.x*256 + threadIdx.x;
  int HWo = Hout*Wout;
  if (idx >= 2*HWo) return;
  int c = idx / HWo;
  int rem = idx - c*HWo;
  int py = rem / Wout, px = rem % Wout;
  float posy = (float)py * (float)(Hin-1) / (float)(Hout-1);
  float posx = (float)px * (float)(Win-1) / (float)(Wout-1);
  int iy = (int)floorf(posy); iy = max(0, min(iy, Hin-2));
  int ix = (int)floorf(posx); ix = max(0, min(ix, Win-2));
  float wy = posy - (float)iy, wx = posx - (float)ix;
  const float* base = cin + (size_t)c*Hin*Win;
  float s00 = 0.f, s10 = 0.f, s01 = 0.f, s11 = 0.f;
  if (subtract){
    if (c == 0){ s00 = (float)ix; s01 = (float)ix; s10 = (float)(ix+1); s11 = (float)(ix+1); }
    else       { s00 = (float)iy; s10 = (float)iy; s01 = (float)(iy+1); s11 = (float)(iy+1); }
  }
  float v00 = base[(size_t)iy*Win + ix]       - s00;
  float v10 = base[(size_t)iy*Win + ix + 1]   - s10;
  float v01 = base[(size_t)(iy+1)*Win + ix]   - s01;
  float v11 = base[(size_t)(iy+1)*Win + ix+1] - s11;
  float val = (1.f-wy)*((1.f-wx)*v00 + wx*v10) + wy*((1.f-wx)*v01 + wx*v11);
  outp[idx] = n * val;
}

// ---------------------------------------------------------------------------
// pack-A: im2col in MFMA A-fragment order, hi/lo split.
// A[m][k], m=pixel, k=ci*KT+tap. Lane l of frag (mt,kt) holds
// A[mt*16 + (l&15)][kt*32 + (l>>4)*8 + e]. Block = 128 short8: hi@lane, lo@lane+64.
// ---------------------------------------------------------------------------
struct Seg { const float* a; const float* b; int c0, c1, flag; };
struct ConvIn { Seg s[4]; };

template<int KTW>   // kernel width 1,3,7
__global__ void k_pack_a(ConvIn cin, short8* __restrict__ out, int H, int W, int ktn)
{
  const int KT = KTW*KTW, P = KTW/2;
  int HW = H*W, MT = HW >> 4;
  int gid = blockIdx.x*256 + threadIdx.x;
  if (gid >= MT*ktn*64) return;
  int lane = gid & 63, blk = gid >> 6;
  int kt = blk % ktn, mt = blk / ktn;
  int m = mt*16 + (lane & 15);
  int x = m % W, y = m / W;
  int kbase = kt*32 + (lane >> 4)*8;
  short8 ohi, olo;
  #pragma unroll
  for (int e = 0; e < 8; e++){
    int k = kbase + e;
    int ci = k / KT, tap = k - ci*KT;
    int dy = tap / KTW - P, dx = tap - (tap/KTW)*KTW - P;
    int xx = x + dx, yy = y + dy;
    float val = 0.f;
    if ((unsigned)xx < (unsigned)W && (unsigned)yy < (unsigned)H){
      int p = yy*W + xx;
      #pragma unroll
      for (int s = 0; s < 4; s++){
        const Seg& sg = cin.s[s];
        if (sg.a && ci >= sg.c0 && ci < sg.c1){
          int cl = ci - sg.c0;
          float v = sg.a[(size_t)cl*HW + p];
          if (sg.flag == 1) v -= (cl == 0) ? (float)xx : (float)yy;
          else if (sg.flag == 2) v *= sg.b[(size_t)cl*HW + p];
          val = v;
        }
      }
    }
    short hi = bf16bits(val);
    ohi[e] = hi;
    olo[e] = bf16bits(val - bf2f(hi));
  }
  out[(size_t)blk*128 + lane]      = ohi;
  out[(size_t)blk*128 + 64 + lane] = olo;
}

// pack-B: weights [Cout][Cin][KT] -> frag order, hi/lo split. Block (kt,ct):
// lane l holds B[kt*32+(l>>4)*8+e][ct*16+(l&15)]. Col-split two-source (zr).
template<int KT>
__global__ void k_pack_b(const float* __restrict__ w0, const float* __restrict__ w1,
                         int split, int Cout, int Cin, short8* __restrict__ out,
                         int nt16, int ktn)
{
  int gid = blockIdx.x*256 + threadIdx.x;
  if (gid >= ktn*nt16*64) return;
  int lane = gid & 63, blk = gid >> 6;
  int ct = blk % nt16, kt = blk / nt16;
  int col = ct*16 + (lane & 15);
  int kbase = kt*32 + (lane >> 4)*8;
  short8 ohi, olo;
  #pragma unroll
  for (int e = 0; e < 8; e++){
    int k = kbase + e, ci = k / KT, tap = k - ci*KT;
    float v = 0.f;
    if (col < Cout && ci < Cin){
      const float* wp = (col < split) ? (w0 + (size_t)col*Cin*KT)
                                      : (w1 + (size_t)(col - split)*Cin*KT);
      v = wp[(size_t)ci*KT + tap];
    }
    short hi = bf16bits(v);
    ohi[e] = hi;
    olo[e] = bf16bits(v - bf2f(hi));
  }
  out[(size_t)blk*128 + lane]      = ohi;
  out[(size_t)blk*128 + 64 + lane] = olo;
}

// ---------------------------------------------------------------------------
// GEMM: wave = 16 rows x 64 cols, WG = 4 waves. grid=(HW/64, ceil(N/64)).
// 3-term split: acc = Ah*Bh + Al*Bh + Ah*Bl.
// ---------------------------------------------------------------------------
struct GSeg { const short8* a; int ktn, ldkt, kt0; };

template<int ACT, int EPI>
__global__ __launch_bounds__(256)
void k_gemm(GSeg s0, GSeg s1, const short8* __restrict__ B,
            const float* __restrict__ bias, float* __restrict__ out,
            int HW, int nt16, int Cout,
            const float* __restrict__ ez, const float* __restrict__ eold)
{
  int lane = threadIdx.x & 63;
  int mt = blockIdx.x*4 + (threadIdx.x >> 6);
  int ct0 = blockIdx.y*4;

  f32x4 a0 = {0.f,0.f,0.f,0.f}, a1 = a0, a2 = a0, a3 = a0;
  int ktg = 0;
  GSeg segs[2] = {s0, s1};
  #pragma unroll
  for (int si = 0; si < 2; si++){
    GSeg sg = segs[si];
    if (sg.ktn > 0){
      const short8* ap = sg.a + ((size_t)mt*sg.ldkt + sg.kt0)*128 + lane;
      const short8* bp = B + ((size_t)ktg*nt16 + ct0)*128 + lane;
      for (int kt = 0; kt < sg.ktn; kt++){
        short8 ah = ap[(size_t)kt*128];
        short8 al = ap[(size_t)kt*128 + 64];
        const short8* bk = bp + (size_t)kt*nt16*128;
        short8 bh0 = bk[0],   bl0 = bk[64];
        short8 bh1 = bk[128], bl1 = bk[192];
        short8 bh2 = bk[256], bl2 = bk[320];
        short8 bh3 = bk[384], bl3 = bk[448];
        a0 = __builtin_amdgcn_mfma_f32_16x16x32_bf16(ah, bh0, a0, 0, 0, 0);
        a1 = __builtin_amdgcn_mfma_f32_16x16x32_bf16(ah, bh1, a1, 0, 0, 0);
        a2 = __builtin_amdgcn_mfma_f32_16x16x32_bf16(ah, bh2, a2, 0, 0, 0);
        a3 = __builtin_amdgcn_mfma_f32_16x16x32_bf16(ah, bh3, a3, 0, 0, 0);
        a0 = __builtin_amdgcn_mfma_f32_16x16x32_bf16(al, bh0, a0, 0, 0, 0);
        a1 = __builtin_amdgcn_mfma_f32_16x16x32_bf16(al, bh1, a1, 0, 0, 0);
        a2 = __builtin_amdgcn_mfma_f32_16x16x32_bf16(al, bh2, a2, 0, 0, 0);
        a3 = __builtin_amdgcn_mfma_f32_16x16x32_bf16(al, bh3, a3, 0, 0, 0);
        a0 = __builtin_amdgcn_mfma_f32_16x16x32_bf16(ah, bl0, a0, 0, 0, 0);
        a1 = __builtin_amdgcn_mfma_f32_16x16x32_bf16(ah, bl1, a1, 0, 0, 0);
        a2 = __builtin_amdgcn_mfma_f32_16x16x32_bf16(ah, bl2, a2, 0, 0, 0);
        a3 = __builtin_amdgcn_mfma_f32_16x16x32_bf16(ah, bl3, a3, 0, 0, 0);
      }
      ktg += sg.ktn;
    }
  }

  int row = mt*16 + ((lane >> 4) << 2);
  int colb = (ct0 << 4) + (lane & 15);

  #define EPILOG(ACCV, J)                                                      \
  { int col = colb + (J)*16;                                                   \
    if (col < Cout){                                                           \
      float bb = bias[col];                                                    \
      _Pragma("unroll")                                                        \
      for (int r = 0; r < 4; r++){                                             \
        float val = ACCV[r] + bb;                                              \
        if (ACT == 1) val = fmaxf(val, 0.f);                                   \
        if (ACT == 2) val = 1.f/(1.f + expf(-val));                            \
        if (ACT == 3) val = tanhf(val);                                        \
        size_t o = (size_t)col*HW + row + r;                                   \
        if constexpr (EPI == 1){ float zz = ez[o]; out[o] = (1.f - zz)*eold[o] + zz*val; } \
        else if constexpr (EPI == 2){ out[o] += val; }                         \
        else out[o] = val;                                                     \
      }                                                                        \
    } }
  EPILOG(a0, 0) EPILOG(a1, 1) EPILOG(a2, 2) EPILOG(a3, 3)
  #undef EPILOG
}

extern "C" void kernel_launch(void* const* d_in, const int* in_sizes, int n_in,
                              void* d_out, int out_size, void* d_ws, size_t ws_size,
                              hipStream_t stream)
{
  (void)in_sizes; (void)n_in; (void)out_size; (void)ws_size;
  const float* f1s[3]    = {(const float*)d_in[0], (const float*)d_in[2], (const float*)d_in[4]};
  const float* f2s[3]    = {(const float*)d_in[1], (const float*)d_in[3], (const float*)d_in[5]};
  const float* net_in[3] = {(const float*)d_in[6], (const float*)d_in[8], (const float*)d_in[10]};
  const float* inp_in[3] = {(const float*)d_in[7], (const float*)d_in[9], (const float*)d_in[11]};
  const float* Wc1 = (const float*)d_in[12]; const float* bc1 = (const float*)d_in[13];
  const float* Wf1 = (const float*)d_in[14]; const float* bf1 = (const float*)d_in[15];
  const float* Wf2 = (const float*)d_in[16]; const float* bf2 = (const float*)d_in[17];
  const float* Wm  = (const float*)d_in[18]; const float* bm  = (const float*)d_in[19];
  const float* Wz  = (const float*)d_in[20]; const float* bz  = (const float*)d_in[21];
  const float* Wr  = (const float*)d_in[22]; const float* br  = (const float*)d_in[23];
  const float* Wq  = (const float*)d_in[24]; const float* bq  = (const float*)d_in[25];
  const float* Wh1 = (const float*)d_in[26]; const float* bh1 = (const float*)d_in[27];
  const float* Wh2 = (const float*)d_in[28]; const float* bh2 = (const float*)d_in[29];

  const int Hs[3] = {96, 48, 24};

  float* ws = (float*)d_ws;
  size_t off = 0;
  auto alloc = [&](size_t nfl)->float*{
    float* p = ws + off;
    off += (nfl + 3) & ~((size_t)3);
    return p;
  };

  float* f2l[3][4]; float* f1h[3]; float* netP[3][2]; float* inpb[3]; float* coords[3];
  for (int si = 0; si < 3; si++){
    int H = Hs[si], HW = H*H;
    for (int l = 0; l < 4; l++) f2l[si][l] = alloc((size_t)(HW >> (2*l))*128);
    f1h[si]     = alloc((size_t)HW*128);
    netP[si][0] = alloc((size_t)96*HW);
    netP[si][1] = alloc((size_t)96*HW);
    inpb[si]    = alloc((size_t)64*HW);
    coords[si]  = alloc((size_t)2*HW);
  }
  const int HWm = 96*96, MTm = HWm/16;
  float* corrfeat = alloc((size_t)196*HWm);
  float* corb     = alloc((size_t)96*HWm);
  float* flo1     = alloc((size_t)64*HWm);
  float* flo2b    = alloc((size_t)32*HWm);
  float* motb     = alloc((size_t)80*HWm);
  float* zrb      = alloc((size_t)192*HWm);
  float* t128     = alloc((size_t)128*HWm);
  // A-pack slots: each (mt,kt) block = 128 short8 = 512 floats (hi+lo)
  float* slotZ = alloc((size_t)MTm*69*512);
  float* slotX = alloc((size_t)MTm*36*512);
  // B packs (hi/lo)
  float* Bc1  = alloc((size_t)7*8*512);
  float* Bf1  = alloc((size_t)4*4*512);
  float* Bf2  = alloc((size_t)18*4*512);
  float* Bm   = alloc((size_t)36*8*512);
  float* Bzr  = alloc((size_t)69*12*512);
  float* Bq   = alloc((size_t)69*8*512);
  float* Bfh1 = alloc((size_t)27*8*512);
  float* Bfh2 = alloc((size_t)36*4*512);
  float* bzr  = alloc(192);

  #define NB(n) dim3((unsigned)nblk((n), 256))

  // ---- one-time: B packs, bias concat ----
  k_pack_b<1><<<NB(7*8*64), 256, 0, stream>>>(Wc1, Wc1, 96, 96, 196, (short8*)Bc1, 8, 7);
  k_pack_b<49><<<NB(4*4*64), 256, 0, stream>>>(Wf1, Wf1, 64, 64, 2, (short8*)Bf1, 4, 4);
  k_pack_b<9><<<NB(18*4*64), 256, 0, stream>>>(Wf2, Wf2, 32, 32, 64, (short8*)Bf2, 4, 18);
  k_pack_b<9><<<NB(36*8*64), 256, 0, stream>>>(Wm, Wm, 80, 80, 128, (short8*)Bm, 8, 36);
  k_pack_b<9><<<NB(69*12*64), 256, 0, stream>>>(Wz, Wr, 96, 192, 242, (short8*)Bzr, 12, 69);
  k_pack_b<9><<<NB(69*8*64), 256, 0, stream>>>(Wq, Wq, 96, 96, 242, (short8*)Bq, 8, 69);
  k_pack_b<9><<<NB(27*8*64), 256, 0, stream>>>(Wh1, Wh1, 128, 128, 96, (short8*)Bfh1, 8, 27);
  k_pack_b<9><<<NB(36*4*64), 256, 0, stream>>>(Wh2, Wh2, 2, 2, 128, (short8*)Bfh2, 4, 36);
  k_cat2<<<dim3(1), 256, 0, stream>>>(bz, br, bzr, 96);

  // ---- per-scale init ----
  for (int si = 0; si < 3; si++){
    int H = Hs[si], HW = H*H;
    k_ew_tanh<<<NB(96*HW), 256, 0, stream>>>(net_in[si], netP[si][0], 96*HW);
    k_ew_relu<<<NB(64*HW), 256, 0, stream>>>(inp_in[si], inpb[si], 64*HW);
    k_init_coords<<<NB(HW), 256, 0, stream>>>(coords[si], H, H);
    k_transpose_hwc<<<NB(HW*128), 256, 0, stream>>>(f2s[si], f2l[si][0], HW);
    k_transpose_hwc<<<NB(HW*128), 256, 0, stream>>>(f1s[si], f1h[si], HW);
    for (int l = 1; l < 4; l++){
      int Hl = H >> l;
      k_pool_hwc<<<NB(Hl*Hl*128), 256, 0, stream>>>(f2l[si][l-1], f2l[si][l], Hl, Hl);
    }
  }

  int cur[3] = {0, 0, 0};
  const int seq[6] = {2, 2, 1, 1, 0, 0};
  Seg zs = {nullptr, nullptr, 0, 0, 0};
  GSeg gz = {nullptr, 0, 0, 0};

  for (int it = 0; it < 6; it++){
    int si = seq[it];
    int H = Hs[si], W = H, HW = H*W;
    int MT = HW/16;
    float s = (si == 0) ? 2.0f : ((si == 1) ? 4.0f : 8.0f);
    float* netc = netP[si][cur[si]];
    float* netn = netP[si][cur[si]^1];
    float* co   = coords[si];
    unsigned gx = (unsigned)(HW/64);
    short8* AZ = (short8*)slotZ;
    short8* AX = (short8*)slotX;

    k_corr_lookup<<<dim3((unsigned)HW), 64, 0, stream>>>(
        f1h[si], f2l[si][0], f2l[si][1], f2l[si][2], f2l[si][3], co, corrfeat, H, W);

    ConvIn I;
    // c1: 1x1, corrfeat(196) -> 96, relu. ktn 7.
    I = ConvIn{{ {corrfeat,nullptr,0,196,0}, zs, zs, zs }};
    k_pack_a<1><<<NB(MT*7*64), 256, 0, stream>>>(I, AX, H, W, 7);
    k_gemm<1,0><<<dim3(gx,2), 256, 0, stream>>>(GSeg{AX,7,7,0}, gz, (short8*)Bc1, bc1, corb, HW, 8, 96, nullptr, nullptr);
    // f1: 7x7, flow(2) -> 64, relu. ktn 4.
    I = ConvIn{{ {co,nullptr,0,2,1}, zs, zs, zs }};
    k_pack_a<7><<<NB(MT*4*64), 256, 0, stream>>>(I, AX, H, W, 4);
    k_gemm<1,0><<<dim3(gx,1), 256, 0, stream>>>(GSeg{AX,4,4,0}, gz, (short8*)Bf1, bf1, flo1, HW, 4, 64, nullptr, nullptr);
    // f2: 3x3, 64 -> 32, relu. ktn 18.
    I = ConvIn{{ {flo1,nullptr,0,64,0}, zs, zs, zs }};
    k_pack_a<3><<<NB(MT*18*64), 256, 0, stream>>>(I, AX, H, W, 18);
    k_gemm<1,0><<<dim3(gx,1), 256, 0, stream>>>(GSeg{AX,18,18,0}, gz, (short8*)Bf2, bf2, flo2b, HW, 4, 32, nullptr, nullptr);
    // m: 3x3, [cor96|flo32] -> 80, relu. ktn 36.
    I = ConvIn{{ {corb,nullptr,0,96,0},{flo2b,nullptr,96,128,0}, zs, zs }};
    k_pack_a<3><<<NB(MT*36*64), 256, 0, stream>>>(I, AX, H, W, 36);
    k_gemm<1,0><<<dim3(gx,2), 256, 0, stream>>>(GSeg{AX,36,36,0}, gz, (short8*)Bm, bm, motb, HW, 8, 80, nullptr, nullptr);
    // zr: 3x3, [net|inp|mot|flow](242) -> 192, sigmoid. ktn 69.
    I = ConvIn{{ {netc,nullptr,0,96,0},{inpb[si],nullptr,96,160,0},{motb,nullptr,160,240,0},{co,nullptr,240,242,1} }};
    k_pack_a<3><<<NB(MT*69*64), 256, 0, stream>>>(I, AZ, H, W, 69);
    k_gemm<2,0><<<dim3(gx,3), 256, 0, stream>>>(GSeg{AZ,69,69,0}, gz, (short8*)Bzr, bzr, zrb, HW, 12, 192, nullptr, nullptr);
    // q: 3x3, [r*net(96) | shared 146] -> 96, tanh + GRU. seg0 ktn 27; seg1 = AZ tail.
    I = ConvIn{{ {zrb + (size_t)96*HW, netc, 0, 96, 2}, zs, zs, zs }};
    k_pack_a<3><<<NB(MT*27*64), 256, 0, stream>>>(I, AX, H, W, 27);
    k_gemm<3,1><<<dim3(gx,2), 256, 0, stream>>>(GSeg{AX,27,27,0}, GSeg{AZ,42,69,27}, (short8*)Bq, bq, netn, HW, 8, 96, zrb, netc);
    // fh1: 3x3, netn(96) -> 128, relu. ktn 27.
    I = ConvIn{{ {netn,nullptr,0,96,0}, zs, zs, zs }};
    k_pack_a<3><<<NB(MT*27*64), 256, 0, stream>>>(I, AX, H, W, 27);
    k_gemm<1,0><<<dim3(gx,2), 256, 0, stream>>>(GSeg{AX,27,27,0}, gz, (short8*)Bfh1, bh1, t128, HW, 8, 128, nullptr, nullptr);
    // fh2: 3x3, t128(128) -> 2, += coords. ktn 36.
    I = ConvIn{{ {t128,nullptr,0,128,0}, zs, zs, zs }};
    k_pack_a<3><<<NB(MT*36*64), 256, 0, stream>>>(I, AX, H, W, 36);
    k_gemm<0,2><<<dim3(gx,1), 256, 0, stream>>>(GSeg{AX,36,36,0}, gz, (short8*)Bfh2, bh2, co, HW, 4, 2, nullptr, nullptr);

    // prediction + coarse-to-fine handoff
    k_upflow<<<NB(2*192*192), 256, 0, stream>>>(co, (float*)d_out + (size_t)it*2*192*192,
                                                H, W, 192, 192, s, 1);
    if (si > 0){
      int Hf = Hs[si-1];
      k_upflow<<<NB(2*Hf*Hf), 256, 0, stream>>>(co, coords[si-1], H, W, Hf, Hf, 2.0f, 0);
    }
    cur[si] ^= 1;
  }
  #undef NB
}